// Round 8
// baseline (37.533 us; speedup 1.0000x reference)
//
#include <hip/hip_runtime.h>
#include <hip/hip_bf16.h>
#include <cstddef>

typedef __attribute__((ext_vector_type(8))) short bf16x8;
typedef __attribute__((ext_vector_type(4))) float f32x4;
typedef __attribute__((ext_vector_type(2))) unsigned int u32x2;

#define NB 4
#define CIN 64
#define COUT 64
#define HH 128
#define WW 128
#define TAPS 9
#define KCH 160      // padded K per chunk (144 real + 16 zero)
#define KTOT 640
#define STRD 82      // sCor row stride in dwords

#define REP 2        // MEASUREMENT PROBE: run the whole pipeline twice so the
                     // dispatch exceeds the harness fill kernels' ~44us and
                     // finally shows up in the rocprof top-5 with counters.

__device__ __forceinline__ unsigned short f2bf(float f) {
    union { float f; unsigned u; } v; v.f = f;
    unsigned u = v.u + 0x7FFFu + ((v.u >> 16) & 1u);   // RNE
    return (unsigned short)(u >> 16);
}

// wB[o][kk], kk = chunk*160 + tap*16 + cl (zero-pad kl 144..159); zrow = 192 zero floats
__global__ void prep_weight(const float* __restrict__ w, unsigned short* __restrict__ wB,
                            float* __restrict__ zrow) {
    int idx = blockIdx.x * blockDim.x + threadIdx.x;
    if (idx < 192) zrow[idx] = 0.f;
    if (idx >= COUT * KTOT) return;
    int o = idx / KTOT;
    int kk = idx - o * KTOT;
    int chunk = kk / KCH;
    int kl = kk - chunk * KCH;
    unsigned short v = 0;
    if (kl < 16 * TAPS) {
        int tap = kl >> 4;
        int cl = kl & 15;
        v = f2bf(w[(o * CIN + chunk * 16 + cl) * TAPS + tap]);
    }
    wB[idx] = v;
}

__launch_bounds__(256)
__global__ void pac_conv(const float* __restrict__ x, const float* __restrict__ Kp,
                         const unsigned short* __restrict__ wB,
                         const float* __restrict__ bias,
                         const float* __restrict__ zrow1,   // zrow+1 (covers idx -1..190)
                         float* __restrict__ out) {
    __shared__ unsigned int sCor[64][STRD];   // 20992 B

    // XCD-chunked bijective swizzle (1024 % 8 == 0)
    const int blk0 = blockIdx.x;
    const int blk  = ((blk0 & 7) << 7) | (blk0 >> 3);

    const int w0 = (blk & 1) * 64;
    const int h  = (blk >> 1) & (HH - 1);
    const int n  = blk >> 8;
    const int t    = threadIdx.x;
    const int lane = t & 63;
    const int wv   = __builtin_amdgcn_readfirstlane(t >> 6);

    // per-pixel adapting kernel -> registers (lane = pixel)
    float kreg[TAPS];
    float ks = 0.f;
    const float* kp = Kp + ((size_t)n * TAPS * HH + h) * WW + w0 + lane;
    #pragma unroll
    for (int tap = 0; tap < TAPS; ++tap) {
        kreg[tap] = kp[(size_t)tap * HH * WW];
        ks += kreg[tap];
    }
    const float inv = 1.0f / ks;

    // zero the K-pad dwords (kl 144..159 -> dw 72..79)
    for (int i = t; i < 64 * 8; i += 256) sCor[i >> 3][72 + (i & 7)] = 0u;

    // w-edge handling: base biased by -1 float; unsigned byte offsets
    const bool mL = (w0 == 0) && (lane == 0);
    const bool mR = (w0 != 0) && (lane == 63);
    const unsigned voffL = (mL ? 1u : (unsigned)lane) * 4u;        // tap l=0
    const unsigned voffC = ((unsigned)lane + 1u) * 4u;             // tap l=1
    const unsigned voffR = (mR ? 64u : (unsigned)lane + 2u) * 4u;  // tap l=2

    const int l15 = lane & 15;
    const int g   = lane >> 4;
    const float bval = bias[wv * 16 + l15];

    f32x4 acc[4];

    #pragma unroll 1
    for (int rep = 0; rep < REP; ++rep) {
        #pragma unroll
        for (int i = 0; i < 4; ++i) acc[i] = (f32x4){0.f, 0.f, 0.f, 0.f};

        #pragma unroll
        for (int chunk = 0; chunk < 4; ++chunk) {
            const int c0 = chunk * 16 + wv * 4;               // wave-uniform
            const float* xb = x + (size_t)(n * CIN + c0) * (HH * WW) + w0 - 1;  // -1 bias

            // ---- issue ALL 36 loads of this chunk before any consumption ----
            float xv[4][TAPS];
            #pragma unroll
            for (int j = 0; j < 4; ++j) {
                #pragma unroll
                for (int k = 0; k < 3; ++k) {
                    const int hh2 = h + k - 1;
                    const float* p = ((unsigned)hh2 < (unsigned)HH)
                        ? (xb + (size_t)j * (HH * WW) + (size_t)hh2 * WW)
                        : (zrow1 - 1);
                    float vL = *(const float*)((const char*)p + voffL);
                    float vC = *(const float*)((const char*)p + voffC);
                    float vR = *(const float*)((const char*)p + voffR);
                    xv[j][k * 3 + 0] = mL ? 0.f : vL;
                    xv[j][k * 3 + 1] = vC;
                    xv[j][k * 3 + 2] = mR ? 0.f : vR;
                }
            }

            // ---- dominate + corrected + bf16 pack ----
            float dom[4];
            #pragma unroll
            for (int j = 0; j < 4; ++j) {
                float s = 0.f;
                #pragma unroll
                for (int tap = 0; tap < TAPS; ++tap) s = fmaf(xv[j][tap], kreg[tap], s);
                dom[j] = s * inv;
            }
            u32x2 cor[TAPS];
            #pragma unroll
            for (int tap = 0; tap < TAPS; ++tap) {
                float c0f = fmaf(kreg[tap], xv[0][tap] - dom[0], dom[0]);
                float c1f = fmaf(kreg[tap], xv[1][tap] - dom[1], dom[1]);
                float c2f = fmaf(kreg[tap], xv[2][tap] - dom[2], dom[2]);
                float c3f = fmaf(kreg[tap], xv[3][tap] - dom[3], dom[3]);
                union { __hip_bfloat162 h2; unsigned int u; } a, b;
                a.h2 = __float22bfloat162_rn(make_float2(c0f, c1f));
                b.h2 = __float22bfloat162_rn(make_float2(c2f, c3f));
                cor[tap] = (u32x2){a.u, b.u};
            }

            if (chunk | rep) __syncthreads();     // previous MFMA readers done
            #pragma unroll
            for (int tap = 0; tap < TAPS; ++tap)
                *reinterpret_cast<u32x2*>(&sCor[lane][tap * 8 + wv * 2]) = cor[tap];
            __syncthreads();

            // ---- MFMA: wave owns 16 outputs x 64 px ----
            const unsigned short* wrow = wB + (size_t)(wv * 16 + l15) * KTOT + chunk * KCH + g * 8;
            #pragma unroll
            for (int step = 0; step < 5; ++step) {
                bf16x8 bfrag = *reinterpret_cast<const bf16x8*>(wrow + step * 32);
                #pragma unroll
                for (int pt = 0; pt < 4; ++pt) {
                    const unsigned int* ap = &sCor[pt * 16 + l15][step * 16 + g * 4];
                    u32x2 alo = *reinterpret_cast<const u32x2*>(ap);
                    u32x2 ahi = *reinterpret_cast<const u32x2*>(ap + 2);
                    union { u32x2 p[2]; bf16x8 f; } af;
                    af.p[0] = alo; af.p[1] = ahi;
                    acc[pt] = __builtin_amdgcn_mfma_f32_16x16x32_bf16(af.f, bfrag, acc[pt], 0, 0, 0);
                }
            }
        }
    }

    // epilogue: direct float4 stores (D rows = 4 consecutive px per thread)
    const int o = wv * 16 + l15;
    float* op = out + (((size_t)n * COUT + o) * HH + h) * WW + w0 + g * 4;
    #pragma unroll
    for (int pt = 0; pt < 4; ++pt) {
        f32x4 v = acc[pt];
        #pragma unroll
        for (int r = 0; r < 4; ++r) v[r] += bval;
        *reinterpret_cast<f32x4*>(op + pt * 16) = v;
    }
}

extern "C" void kernel_launch(void* const* d_in, const int* in_sizes, int n_in,
                              void* d_out, int out_size, void* d_ws, size_t ws_size,
                              hipStream_t stream) {
    const float* x    = (const float*)d_in[0];
    const float* Kp   = (const float*)d_in[1];
    const float* wgt  = (const float*)d_in[2];
    const float* bias = (const float*)d_in[3];
    float* out = (float*)d_out;
    unsigned short* wB = (unsigned short*)d_ws;              // 81920 B
    float* zrow = (float*)((char*)d_ws + 81920);             // 192 zero floats

    prep_weight<<<(COUT * KTOT + 255) / 256, 256, 0, stream>>>(wgt, wB, zrow);

    pac_conv<<<NB * HH * (WW / 64), 256, 0, stream>>>(x, Kp, wB, bias, zrow + 1, out);
}

// Round 9
// 28.858 us; speedup vs baseline: 1.3006x; 1.3006x over previous
//
#include <hip/hip_runtime.h>
#include <hip/hip_bf16.h>
#include <cstddef>

typedef __attribute__((ext_vector_type(8))) short bf16x8;
typedef __attribute__((ext_vector_type(4))) float f32x4;
typedef __attribute__((ext_vector_type(2))) unsigned int u32x2;

#define NB 4
#define CIN 64
#define COUT 64
#define HH 128
#define WW 128
#define TAPS 9
#define STRD 82      // sCor row stride in dwords

__device__ __forceinline__ unsigned short f2bf(float f) {
    union { float f; unsigned u; } v; v.f = f;
    unsigned u = v.u + 0x7FFFu + ((v.u >> 16) & 1u);   // RNE
    return (unsigned short)(u >> 16);
}

// Coalesced frag layout: wBv[((wv*20 + chunk*5 + step)*64 + lane)*8 + e]
// lane = g*16 + l15, o = wv*16 + l15, kk = step*32 + g*8 + e (tap=kk>>4, cl=kk&15)
// kk >= 144 zero-padded. 80 frag-groups * 64 lanes * 8 shorts = 40960 shorts.
__global__ void prep_weight(const float* __restrict__ w, unsigned short* __restrict__ wBv) {
    int idx = blockIdx.x * blockDim.x + threadIdx.x;
    if (idx >= 40960) return;
    int e    = idx & 7;
    int lane = (idx >> 3) & 63;
    int fid  = idx >> 9;               // wv*20 + chunk*5 + step
    int wv   = fid / 20;
    int rem  = fid - wv * 20;
    int chunk = rem / 5;
    int step  = rem - chunk * 5;
    int l15 = lane & 15, g = lane >> 4;
    int o  = wv * 16 + l15;
    int kk = step * 32 + g * 8 + e;
    unsigned short v = 0;
    if (kk < 144) {
        int tap = kk >> 4;
        int cl  = kk & 15;
        v = f2bf(w[(o * CIN + chunk * 16 + cl) * TAPS + tap]);
    }
    wBv[idx] = v;
}

__launch_bounds__(256)
__global__ void pac_conv(const float* __restrict__ x, const float* __restrict__ Kp,
                         const unsigned short* __restrict__ wBv,
                         const float* __restrict__ bias,
                         float* __restrict__ out) {
    __shared__ unsigned int sCor[64][STRD];   // 20992 B

    // XCD-chunked bijective swizzle (1024 % 8 == 0)
    const int blk0 = blockIdx.x;
    const int blk  = ((blk0 & 7) << 7) | (blk0 >> 3);

    const int w0 = (blk & 1) * 64;
    const int h  = (blk >> 1) & (HH - 1);
    const int n  = blk >> 8;
    const int t    = threadIdx.x;
    const int lane = t & 63;
    const int wv   = __builtin_amdgcn_readfirstlane(t >> 6);

    // w-edge handling: base biased by -1 float; unsigned byte offsets (always in-bounds)
    const bool mL = (w0 == 0) && (lane == 0);
    const bool mR = (w0 != 0) && (lane == 63);
    const unsigned voffL = (mL ? 1u : (unsigned)lane) * 4u;        // tap l=0
    const unsigned voffC = ((unsigned)lane + 1u) * 4u;             // tap l=1
    const unsigned voffR = (mR ? 64u : (unsigned)lane + 2u) * 4u;  // tap l=2

    // batched x loads for one chunk (clamped rows; uniform-hok zeroing; MLP=36)
    auto load_x = [&](int chunk, float (&xv)[4][TAPS]) {
        const int c0 = chunk * 16 + wv * 4;               // wave-uniform
        const float* xb = x + (size_t)(n * CIN + c0) * (HH * WW) + w0 - 1;  // -1 bias
        #pragma unroll
        for (int j = 0; j < 4; ++j) {
            #pragma unroll
            for (int k = 0; k < 3; ++k) {
                const int hh2 = h + k - 1;
                const bool hok = (unsigned)hh2 < (unsigned)HH;
                const int hc = hok ? hh2 : (hh2 < 0 ? 0 : HH - 1);
                const float* p = xb + (size_t)j * (HH * WW) + (size_t)hc * WW;
                float vL = *(const float*)((const char*)p + voffL);
                float vC = *(const float*)((const char*)p + voffC);
                float vR = *(const float*)((const char*)p + voffR);
                xv[j][k * 3 + 0] = (hok && !mL) ? vL : 0.f;
                xv[j][k * 3 + 1] = hok ? vC : 0.f;
                xv[j][k * 3 + 2] = (hok && !mR) ? vR : 0.f;
            }
        }
    };

    // ---- issue chunk-0 x loads FIRST (deepest cold misses front-loaded) ----
    float xv0[4][TAPS];
    load_x(0, xv0);

    // per-pixel adapting kernel -> registers (lane = pixel)
    float kreg[TAPS];
    float ks = 0.f;
    const float* kp = Kp + ((size_t)n * TAPS * HH + h) * WW + w0 + lane;
    #pragma unroll
    for (int tap = 0; tap < TAPS; ++tap) {
        kreg[tap] = kp[(size_t)tap * HH * WW];
        ks += kreg[tap];
    }
    const float inv = 1.0f / ks;

    // zero the K-pad dwords (kl 144..159 -> dw 72..79) so stale LDS (possible
    // NaN patterns) never meets the zero B-pad as NaN*0
    for (int i = t; i < 64 * 8; i += 256) sCor[i >> 3][72 + (i & 7)] = 0u;

    const int l15 = lane & 15;
    const int g   = lane >> 4;
    const float bval = bias[wv * 16 + l15];

    f32x4 acc[4];
    #pragma unroll
    for (int i = 0; i < 4; ++i) acc[i] = (f32x4){0.f, 0.f, 0.f, 0.f};

    #pragma unroll
    for (int chunk = 0; chunk < 4; ++chunk) {
        float xv[4][TAPS];
        if (chunk == 0) {
            #pragma unroll
            for (int j = 0; j < 4; ++j)
                #pragma unroll
                for (int tap = 0; tap < TAPS; ++tap) xv[j][tap] = xv0[j][tap];
        } else {
            load_x(chunk, xv);
        }

        // ---- dominate + corrected + bf16 pack ----
        float dom[4];
        #pragma unroll
        for (int j = 0; j < 4; ++j) {
            float s = 0.f;
            #pragma unroll
            for (int tap = 0; tap < TAPS; ++tap) s = fmaf(xv[j][tap], kreg[tap], s);
            dom[j] = s * inv;
        }
        u32x2 cor[TAPS];
        #pragma unroll
        for (int tap = 0; tap < TAPS; ++tap) {
            float c0f = fmaf(kreg[tap], xv[0][tap] - dom[0], dom[0]);
            float c1f = fmaf(kreg[tap], xv[1][tap] - dom[1], dom[1]);
            float c2f = fmaf(kreg[tap], xv[2][tap] - dom[2], dom[2]);
            float c3f = fmaf(kreg[tap], xv[3][tap] - dom[3], dom[3]);
            union { __hip_bfloat162 h2; unsigned int u; } a, b;
            a.h2 = __float22bfloat162_rn(make_float2(c0f, c1f));
            b.h2 = __float22bfloat162_rn(make_float2(c2f, c3f));
            cor[tap] = (u32x2){a.u, b.u};
        }

        if (chunk) __syncthreads();           // previous MFMA readers done
        #pragma unroll
        for (int tap = 0; tap < TAPS; ++tap)
            *reinterpret_cast<u32x2*>(&sCor[lane][tap * 8 + wv * 2]) = cor[tap];
        __syncthreads();

        // ---- MFMA: wave owns 16 outputs x 64 px; coalesced B-frag loads ----
        const unsigned short* wfb =
            wBv + (((size_t)(wv * 20 + chunk * 5) << 6) + lane) * 8;   // +step*512
        #pragma unroll
        for (int step = 0; step < 5; ++step) {
            bf16x8 bfrag = *reinterpret_cast<const bf16x8*>(wfb + (step << 9));
            #pragma unroll
            for (int pt = 0; pt < 4; ++pt) {
                const unsigned int* ap = &sCor[pt * 16 + l15][step * 16 + g * 4];
                u32x2 alo = *reinterpret_cast<const u32x2*>(ap);
                u32x2 ahi = *reinterpret_cast<const u32x2*>(ap + 2);
                union { u32x2 p[2]; bf16x8 f; } af;
                af.p[0] = alo; af.p[1] = ahi;
                acc[pt] = __builtin_amdgcn_mfma_f32_16x16x32_bf16(af.f, bfrag, acc[pt], 0, 0, 0);
            }
        }
    }

    // epilogue: direct float4 stores (D rows = 4 consecutive px per thread)
    const int o = wv * 16 + l15;
    float* op = out + (((size_t)n * COUT + o) * HH + h) * WW + w0 + g * 4;
    #pragma unroll
    for (int pt = 0; pt < 4; ++pt) {
        f32x4 v = acc[pt];
        #pragma unroll
        for (int r = 0; r < 4; ++r) v[r] += bval;
        *reinterpret_cast<f32x4*>(op + pt * 16) = v;
    }
}

extern "C" void kernel_launch(void* const* d_in, const int* in_sizes, int n_in,
                              void* d_out, int out_size, void* d_ws, size_t ws_size,
                              hipStream_t stream) {
    const float* x    = (const float*)d_in[0];
    const float* Kp   = (const float*)d_in[1];
    const float* wgt  = (const float*)d_in[2];
    const float* bias = (const float*)d_in[3];
    float* out = (float*)d_out;
    unsigned short* wBv = (unsigned short*)d_ws;             // 81920 B

    prep_weight<<<160, 256, 0, stream>>>(wgt, wBv);

    pac_conv<<<NB * HH * (WW / 64), 256, 0, stream>>>(x, Kp, wBv, bias, out);
}